// Round 2
// baseline (4534.898 us; speedup 1.0000x reference)
//
#include <hip/hip_runtime.h>

// Problem constants (from reference setup_inputs)
#define N_NODES 100001
#define DT 0.1f
#define N_STEPS 100

// ---------------------------------------------------------------------------
// CSR construction (indices are INT32 — harness passes integer inputs as int)
// ---------------------------------------------------------------------------

__global__ void hist_kernel(const int* __restrict__ rows,
                            int* __restrict__ counts, int E) {
    int e = blockIdx.x * blockDim.x + threadIdx.x;
    if (e < E) atomicAdd(&counts[rows[e]], 1);
}

// Single-block hierarchical exclusive scan over n counts -> row_ptr[0..n]
__global__ __launch_bounds__(1024) void scan_kernel(const int* __restrict__ counts,
                                                    int* __restrict__ row_ptr, int n) {
    __shared__ int tmp[1024];
    int tid = threadIdx.x;
    int per = (n + 1023) >> 10;           // elements per thread
    int start = tid * per;
    int end = min(start + per, n);
    int sum = 0;
    for (int i = start; i < end; ++i) sum += counts[i];
    tmp[tid] = sum;
    __syncthreads();
    // Hillis-Steele inclusive scan of the 1024 partials
    for (int d = 1; d < 1024; d <<= 1) {
        int v = (tid >= d) ? tmp[tid - d] : 0;
        __syncthreads();
        tmp[tid] += v;
        __syncthreads();
    }
    int off = tmp[tid] - sum;             // exclusive prefix for this chunk
    for (int i = start; i < end; ++i) { row_ptr[i] = off; off += counts[i]; }
    if (tid == 1023) row_ptr[n] = tmp[1023];
}

__global__ void fill_kernel(const int* __restrict__ rows,
                            const int* __restrict__ cols,
                            const float* __restrict__ pol,
                            const int* __restrict__ row_ptr,
                            int* __restrict__ cursor,
                            int* __restrict__ csr_col,
                            float* __restrict__ csr_val, int E) {
    int e = blockIdx.x * blockDim.x + threadIdx.x;
    if (e >= E) return;
    int r = rows[e];
    int c = cols[e];
    // Reference masks: row-0 entries -> 0, except (0,0) entries -> 1
    float v = (r == 0) ? ((c == 0) ? 1.0f : 0.0f) : DT * pol[e];
    int pos = row_ptr[r] + atomicAdd(&cursor[r], 1);
    csr_col[pos] = c;
    csr_val[pos] = v;
}

// ---------------------------------------------------------------------------
// Iteration kernels
// ---------------------------------------------------------------------------

__global__ void init_x_kernel(float* __restrict__ x, int n) {
    int i = blockIdx.x * blockDim.x + threadIdx.x;
    if (i < n) x[i] = 1.0f;
}

// One wave (64 lanes) per row (avg 64 edges/row). Diagonal handled
// analytically: row 0 diag = 1.0 (masked), rows >0 diag = 1-DT = 0.9.
__global__ __launch_bounds__(256) void spmv_kernel(const int* __restrict__ row_ptr,
                                                   const int* __restrict__ csr_col,
                                                   const float* __restrict__ csr_val,
                                                   const float* __restrict__ x,
                                                   float* __restrict__ y, int n) {
    int wave = (blockIdx.x * blockDim.x + threadIdx.x) >> 6;
    int lane = threadIdx.x & 63;
    if (wave >= n) return;
    int s = row_ptr[wave];
    int e = row_ptr[wave + 1];
    float acc = 0.0f;
    for (int i = s + lane; i < e; i += 64)
        acc += csr_val[i] * x[csr_col[i]];
    #pragma unroll
    for (int off = 32; off > 0; off >>= 1)
        acc += __shfl_down(acc, off, 64);
    if (lane == 0) {
        float diag = (wave == 0) ? 1.0f : (1.0f - DT);
        y[wave] = diag * x[wave] + acc;
    }
}

// ---------------------------------------------------------------------------
// COO fallback (if workspace can't hold CSR): y = diag*x, then atomic scatter
// ---------------------------------------------------------------------------

__global__ void coo_init_kernel(const float* __restrict__ x,
                                float* __restrict__ y, int n) {
    int i = blockIdx.x * blockDim.x + threadIdx.x;
    if (i < n) y[i] = ((i == 0) ? 1.0f : (1.0f - DT)) * x[i];
}

__global__ void coo_edge_kernel(const int* __restrict__ rows,
                                const int* __restrict__ cols,
                                const float* __restrict__ pol,
                                const float* __restrict__ x,
                                float* __restrict__ y, int E) {
    int e = blockIdx.x * blockDim.x + threadIdx.x;
    if (e >= E) return;
    int r = rows[e];
    int c = cols[e];
    float v = (r == 0) ? ((c == 0) ? 1.0f : 0.0f) : DT * pol[e];
    if (v != 0.0f) atomicAdd(&y[r], v * x[c]);
}

// ---------------------------------------------------------------------------
// Epilogue: max|x[1:]| then normalize
// ---------------------------------------------------------------------------

__global__ void max_kernel(const float* __restrict__ x, unsigned* __restrict__ maxbits, int n) {
    float m = 0.0f;
    for (int i = 1 + blockIdx.x * blockDim.x + threadIdx.x; i < n; i += gridDim.x * blockDim.x)
        m = fmaxf(m, fabsf(x[i]));
    #pragma unroll
    for (int off = 32; off > 0; off >>= 1)
        m = fmaxf(m, __shfl_down(m, off, 64));
    __shared__ float smax[4];
    int lane = threadIdx.x & 63, w = threadIdx.x >> 6;
    if (lane == 0) smax[w] = m;
    __syncthreads();
    if (threadIdx.x == 0) {
        float mm = smax[0];
        for (int i = 1; i < (int)(blockDim.x >> 6); ++i) mm = fmaxf(mm, smax[i]);
        // spins are non-negative (all coefficients >= 0, x0 = 1) ->
        // uint compare == float compare
        atomicMax(maxbits, __float_as_uint(mm));
    }
}

__global__ void normalize_kernel(const float* __restrict__ x,
                                 const unsigned* __restrict__ maxbits,
                                 float* __restrict__ out, int n) {
    int i = blockIdx.x * blockDim.x + threadIdx.x;
    if (i >= n) return;
    if (i == 0) { out[0] = 1.0f; return; }
    float mv = __uint_as_float(*maxbits);
    out[i] = x[i] / mv;
}

// ---------------------------------------------------------------------------
// Launch
// ---------------------------------------------------------------------------

static inline size_t align_up(size_t v, size_t a) { return (v + a - 1) & ~(a - 1); }

extern "C" void kernel_launch(void* const* d_in, const int* in_sizes, int n_in,
                              void* d_out, int out_size, void* d_ws, size_t ws_size,
                              hipStream_t stream) {
    // Harness passes integer inputs as INT32 regardless of the reference's
    // nominal int64 (see harness header). adj_ind is (2, E) flattened.
    const int* adj   = (const int*)d_in[0];
    const float* pol = (const float*)d_in[1];
    const int E = in_sizes[1];
    const int N = N_NODES;
    const int* rows = adj;
    const int* cols = adj + E;

    const int TB = 256;
    const int eb = (E + TB - 1) / TB;
    const int nb = (N + TB - 1) / TB;

    // Workspace budget check (ws_size is constant across calls -> this branch
    // does identical work every call; safe for graph capture).
    const size_t sz_rowptr = align_up(sizeof(int) * (size_t)(N + 1), 256);
    const size_t sz_counts = align_up(sizeof(int) * (size_t)N, 256);
    const size_t sz_col    = align_up(sizeof(int) * (size_t)E, 256);
    const size_t sz_val    = align_up(sizeof(float) * (size_t)E, 256);
    const size_t sz_x      = align_up(sizeof(float) * (size_t)N, 256);
    const size_t need_csr  = sz_rowptr + sz_counts + sz_col + sz_val + 2 * sz_x + 256;

    if (ws_size >= need_csr) {
        // -------- CSR path --------
        char* p = (char*)d_ws;
        int* row_ptr   = (int*)p;      p += sz_rowptr;
        int* counts    = (int*)p;      p += sz_counts;
        int* csr_col   = (int*)p;      p += sz_col;
        float* csr_val = (float*)p;    p += sz_val;
        float* x0      = (float*)p;    p += sz_x;
        float* x1      = (float*)p;    p += sz_x;
        unsigned* maxb = (unsigned*)p;

        hipMemsetAsync(counts, 0, sizeof(int) * (size_t)N, stream);
        hist_kernel<<<eb, TB, 0, stream>>>(rows, counts, E);
        scan_kernel<<<1, 1024, 0, stream>>>(counts, row_ptr, N);
        hipMemsetAsync(counts, 0, sizeof(int) * (size_t)N, stream);  // reuse as cursor
        fill_kernel<<<eb, TB, 0, stream>>>(rows, cols, pol, row_ptr, counts,
                                           csr_col, csr_val, E);

        init_x_kernel<<<nb, TB, 0, stream>>>(x0, N);
        float* xin = x0;
        float* xout = x1;
        const int spmv_blocks = (N * 64 + TB - 1) / TB;   // one wave per row
        for (int s = 0; s < N_STEPS; ++s) {
            spmv_kernel<<<spmv_blocks, TB, 0, stream>>>(row_ptr, csr_col, csr_val,
                                                        xin, xout, N);
            float* t = xin; xin = xout; xout = t;
        }

        hipMemsetAsync(maxb, 0, sizeof(unsigned), stream);
        max_kernel<<<512, TB, 0, stream>>>(xin, maxb, N);
        normalize_kernel<<<nb, TB, 0, stream>>>(xin, maxb, (float*)d_out, N);
    } else {
        // -------- COO fallback (~800 KB scratch) --------
        char* p = (char*)d_ws;
        float* x0      = (float*)p;    p += sz_x;
        float* x1      = (float*)p;    p += sz_x;
        unsigned* maxb = (unsigned*)p;

        init_x_kernel<<<nb, TB, 0, stream>>>(x0, N);
        float* xin = x0;
        float* xout = x1;
        for (int s = 0; s < N_STEPS; ++s) {
            coo_init_kernel<<<nb, TB, 0, stream>>>(xin, xout, N);
            coo_edge_kernel<<<eb, TB, 0, stream>>>(rows, cols, pol, xin, xout, E);
            float* t = xin; xin = xout; xout = t;
        }

        hipMemsetAsync(maxb, 0, sizeof(unsigned), stream);
        max_kernel<<<512, TB, 0, stream>>>(xin, maxb, N);
        normalize_kernel<<<nb, TB, 0, stream>>>(xin, maxb, (float*)d_out, N);
    }
}